// Round 8
// baseline (228.694 us; speedup 1.0000x reference)
//
#include <hip/hip_runtime.h>
#include <cstdint>

#define N_NODES 50000
#define N_EDGES 800000
#define N_FEAT 256
#define HIDDEN 128
#define N_CLASSES 40
#define NBUCKET 196         // dst >> 8
#define EPB 3125            // edges per hist/partition block (256 * 3125 = 800000)
#define ROWS_PAD 50048      // 782 * 64
#define H2S 64              // h2 row stride (ushorts) = 128 B aligned

typedef __attribute__((ext_vector_type(8))) short bf16x8;
typedef __attribute__((ext_vector_type(4))) float f32x4;

__device__ inline ushort f2bf(float f) {
    union { float f; uint u; } v; v.f = f;
    uint u = v.u;
    u += 0x7fff + ((u >> 16) & 1);   // round-to-nearest-even
    return (ushort)(u >> 16);
}
__device__ inline float bflo(uint u) {
    union { uint u; float f; } v; v.u = u << 16; return v.f;
}
__device__ inline float bfhi(uint u) {
    union { uint u; float f; } v; v.u = u & 0xffff0000u; return v.f;
}

// ---------------- 1) per-block bucket histogram + W1 repack ----------------

__global__ void hist_repack(const int* __restrict__ dst, int* __restrict__ histT,
                            const float* __restrict__ W1, ushort* __restrict__ Bp1) {
    __shared__ int h[NBUCKET];
    int blk = blockIdx.x, t = threadIdx.x;
    int gid = blk * 256 + t;
    if (gid < 32768) {       // W1 repack into MFMA B-frag order
        int j = gid & 7, lane = (gid >> 3) & 63, kt = (gid >> 9) & 7, nt = gid >> 12;
        int k = kt * 32 + (lane >> 4) * 8 + j;
        int n = nt * 16 + (lane & 15);
        Bp1[gid] = f2bf(W1[k * HIDDEN + n]);
    }
    if (t < NBUCKET) h[t] = 0;
    __syncthreads();
    int base = blk * EPB;
    for (int i = t; i < EPB; i += 256)
        atomicAdd(&h[dst[base + i] >> 8], 1);
    __syncthreads();
    if (t < NBUCKET) histT[t * 256 + blk] = h[t];   // bucket-major
}

// ---------------- 2) inclusive scan of histT chunks (chunk = bucket) ----------------

__global__ void scan_a(const int* __restrict__ in, int* __restrict__ incl,
                       int* __restrict__ bsum) {
    __shared__ int s[256];
    int blk = blockIdx.x, t = threadIdx.x;
    int i = blk * 256 + t;
    s[t] = in[i];
    __syncthreads();
    for (int off = 1; off < 256; off <<= 1) {
        int t2 = 0;
        if (t >= off) t2 = s[t - off];
        __syncthreads();
        s[t] += t2;
        __syncthreads();
    }
    incl[i] = s[t];
    if (t == 255) bsum[blk] = s[255];   // bsum[bucket] = edges in bucket
}

// ---------------- 3) partition edges into bucket-grouped ebuf (inline fixup) ----------------

__global__ void partition_k(const int* __restrict__ src, const int* __restrict__ dst,
                            const int* __restrict__ incl, const int* __restrict__ hist,
                            const int* __restrict__ bsum, uint* __restrict__ ebuf) {
    __shared__ int ebase[NBUCKET];
    __shared__ int cur[NBUCKET];
    __shared__ int s[256];
    int blk = blockIdx.x, t = threadIdx.x;
    s[t] = (t < NBUCKET) ? bsum[t] : 0;
    __syncthreads();
    for (int off = 1; off < 256; off <<= 1) {
        int t2 = 0;
        if (t >= off) t2 = s[t - off];
        __syncthreads();
        s[t] += t2;
        __syncthreads();
    }
    if (t < NBUCKET) {
        int bucket_start = (t > 0) ? s[t - 1] : 0;
        // edges of bucket t in blocks < blk  =  incl - hist
        ebase[t] = bucket_start + incl[t * 256 + blk] - hist[t * 256 + blk];
        cur[t] = 0;
    }
    __syncthreads();
    int eb = blk * EPB;
    for (int i = t; i < EPB; i += 256) {
        int d = dst[eb + i], sv = src[eb + i];
        int bk = d >> 8;
        int p = ebase[bk] + atomicAdd(&cur[bk], 1);
        ebuf[p] = ((uint)d << 16) | (uint)sv;
    }
}

// ---------------- 4) per-bucket: degree + dinv + local rowptr + CSR fill ----------------

__global__ void bucket_csr(const uint* __restrict__ ebuf, const int* __restrict__ bsum,
                           int* __restrict__ deg, float* __restrict__ dinv,
                           int* __restrict__ rowptr, int* __restrict__ esrc) {
    __shared__ int cnt[256];
    __shared__ int s[256];
    __shared__ int exc[256];
    __shared__ int cur[256];
    int b = blockIdx.x, t = threadIdx.x;
    // bucket range from bsum scan
    s[t] = (t < NBUCKET) ? bsum[t] : 0;
    __syncthreads();
    for (int off = 1; off < 256; off <<= 1) {
        int t2 = 0;
        if (t >= off) t2 = s[t - off];
        __syncthreads();
        s[t] += t2;
        __syncthreads();
    }
    int beg = (b > 0) ? s[b - 1] : 0;
    int end = s[b];
    __syncthreads();
    cnt[t] = 0;
    cur[t] = 0;
    __syncthreads();
    for (int i = beg + t; i < end; i += 256)
        atomicAdd(&cnt[(ebuf[i] >> 16) & 255], 1);
    __syncthreads();
    int d = cnt[t];
    s[t] = d;
    __syncthreads();
    for (int off = 1; off < 256; off <<= 1) {
        int t2 = 0;
        if (t >= off) t2 = s[t - off];
        __syncthreads();
        s[t] += t2;
        __syncthreads();
    }
    exc[t] = s[t] - d;
    int node = b * 256 + t;
    if (node < N_NODES) {
        deg[node] = d;
        dinv[node] = rsqrtf((float)(d + 1));        // +1 self-loop
        rowptr[node] = beg + exc[t];
    }
    __syncthreads();
    for (int i = beg + t; i < end; i += 256) {
        uint u = ebuf[i];
        int dl = (int)(u >> 16) & 255;
        int pos = beg + exc[dl] + atomicAdd(&cur[dl], 1);
        esrc[pos] = (int)(u & 0xffffu);
    }
}

// ---------------- GEMM1: h1b[N,128] = bf16(x[N,256]) @ W1  (MFMA) ----------------

#define XS_STRIDE 264   // 256 + 8 bf16 pad

__global__ __launch_bounds__(256) void gemm1_mfma(const float* __restrict__ x,
                                                  const ushort* __restrict__ Bp,
                                                  ushort* __restrict__ h1b) {
    __shared__ ushort xs[64 * XS_STRIDE];   // 33792 B
    int t = threadIdx.x;
    int row0 = blockIdx.x * 64;
#pragma unroll
    for (int i = 0; i < 16; ++i) {
        int idx = t + i * 256;
        int r = idx >> 6, kg = idx & 63;
        int row = row0 + r;
        float4 v = make_float4(0.f, 0.f, 0.f, 0.f);
        if (row < N_NODES) v = *(const float4*)(x + (size_t)row * N_FEAT + kg * 4);
        ushort4 u;
        u.x = f2bf(v.x); u.y = f2bf(v.y); u.z = f2bf(v.z); u.w = f2bf(v.w);
        *(ushort4*)(&xs[r * XS_STRIDE + kg * 4]) = u;
    }
    __syncthreads();
    int lane = t & 63, w = t >> 6;
    int r = lane & 15, q = lane >> 4;
    f32x4 acc[8] = {};
    for (int kt = 0; kt < 8; ++kt) {
        bf16x8 a = *(const bf16x8*)(&xs[(w * 16 + r) * XS_STRIDE + kt * 32 + q * 8]);
#pragma unroll
        for (int nt = 0; nt < 8; ++nt) {
            bf16x8 b = *(const bf16x8*)(Bp + (((nt * 8 + kt) * 64) + lane) * 8);
            acc[nt] = __builtin_amdgcn_mfma_f32_16x16x32_bf16(a, b, acc[nt], 0, 0, 0);
        }
    }
#pragma unroll
    for (int nt = 0; nt < 8; ++nt) {
        int col = nt * 16 + r;
#pragma unroll
        for (int reg = 0; reg < 4; ++reg) {
            int row = row0 + w * 16 + q * 4 + reg;
            if (row < N_NODES) h1b[(size_t)row * HIDDEN + col] = f2bf(acc[nt][reg]);
        }
    }
}

// ---------------- fused layer-1 aggregation + layer-2 linear ----------------
// wave = 1 node. Gather phase: halves own alternating edges, lane l<32 covers
// feats 4l..4l+3 (uint2 loads). Then row -> LDS (fp32), lanes 0..39 compute
// h2[v][c] = relu_row . W2[:,c] with W2 staged fp32 in LDS.

__global__ __launch_bounds__(256) void agg1_gemm2(
        const int* __restrict__ rowptr, const int* __restrict__ deg,
        const int* __restrict__ esrc, const float* __restrict__ dinv,
        const ushort* __restrict__ h1b, const float* __restrict__ b1,
        const float* __restrict__ W2, ushort* __restrict__ h2b) {
    __shared__ float Ws[HIDDEN * N_CLASSES];   // 20480 B
    __shared__ float rowbuf[4][HIDDEN];        // 2048 B
    int t = threadIdx.x;
    for (int i = t; i < HIDDEN * N_CLASSES / 4; i += 256)
        ((float4*)Ws)[i] = ((const float4*)W2)[i];

    int w = t >> 6, lane = t & 63;
    int v = blockIdx.x * 4 + w;                // grid 12500 -> v < 50000 always
    int half = lane >> 5, l = lane & 31;
    int beg = rowptr[v], d = deg[v];
    float dv = dinv[v];
    float ax = 0.f, ay = 0.f, az = 0.f, aw = 0.f;
    if (half == 0) {    // self-loop term counted once
        uint2 hv = *(const uint2*)(h1b + (size_t)v * HIDDEN + l * 4);
        float dd = dv * dv;
        ax = bflo(hv.x) * dd; ay = bfhi(hv.x) * dd;
        az = bflo(hv.y) * dd; aw = bfhi(hv.y) * dd;
    }
    int e_l = (lane < d) ? esrc[beg + lane] : 0;
    float w_l = (lane < d) ? dinv[e_l] : 0.f;   // 0 weight: invalid edges vanish
    int dm = min(d, 64);
    int i = 0;
    for (; i + 4 <= dm; i += 4) {
        int s0 = __shfl(e_l, i + half, 64);
        int s1 = __shfl(e_l, i + 2 + half, 64);
        float g0 = __shfl(w_l, i + half, 64) * dv;
        float g1 = __shfl(w_l, i + 2 + half, 64) * dv;
        uint2 h0 = *(const uint2*)(h1b + (size_t)s0 * HIDDEN + l * 4);
        uint2 h1v = *(const uint2*)(h1b + (size_t)s1 * HIDDEN + l * 4);
        ax = fmaf(bflo(h0.x), g0, ax);  ay = fmaf(bfhi(h0.x), g0, ay);
        az = fmaf(bflo(h0.y), g0, az);  aw = fmaf(bfhi(h0.y), g0, aw);
        ax = fmaf(bflo(h1v.x), g1, ax); ay = fmaf(bfhi(h1v.x), g1, ay);
        az = fmaf(bflo(h1v.y), g1, az); aw = fmaf(bfhi(h1v.y), g1, aw);
    }
    for (; i < dm; i += 2) {          // pair tail (g=0 guards odd counts)
        int s0 = __shfl(e_l, i + half, 64);
        float g0 = __shfl(w_l, i + half, 64) * dv;
        uint2 h0 = *(const uint2*)(h1b + (size_t)s0 * HIDDEN + l * 4);
        ax = fmaf(bflo(h0.x), g0, ax); ay = fmaf(bfhi(h0.x), g0, ay);
        az = fmaf(bflo(h0.y), g0, az); aw = fmaf(bfhi(h0.y), g0, aw);
    }
    for (int j = 64 + half; j < d; j += 2) {   // rare deg>64 tail
        int s = esrc[beg + j];
        float g = dinv[s] * dv;
        uint2 hs = *(const uint2*)(h1b + (size_t)s * HIDDEN + l * 4);
        ax = fmaf(bflo(hs.x), g, ax); ay = fmaf(bfhi(hs.x), g, ay);
        az = fmaf(bflo(hs.y), g, az); aw = fmaf(bfhi(hs.y), g, aw);
    }
    ax += __shfl_xor(ax, 32, 64);
    ay += __shfl_xor(ay, 32, 64);
    az += __shfl_xor(az, 32, 64);
    aw += __shfl_xor(aw, 32, 64);
    if (half == 0) {
        float4 bb = ((const float4*)b1)[l];
        ax += bb.x; ay += bb.y; az += bb.z; aw += bb.w;
        float4 r;
        r.x = ax > 0.f ? ax : 0.f;
        r.y = ay > 0.f ? ay : 0.f;
        r.z = az > 0.f ? az : 0.f;
        r.w = aw > 0.f ? aw : 0.f;
        *(float4*)(&rowbuf[w][l * 4]) = r;
    }
    __syncthreads();   // rowbuf + Ws visible
    if (lane < N_CLASSES) {
        float acc = 0.f;
#pragma unroll 8
        for (int k = 0; k < HIDDEN; ++k)
            acc = fmaf(rowbuf[w][k], Ws[k * N_CLASSES + lane], acc);
        h2b[(size_t)v * H2S + lane] = f2bf(acc);
    }
}

// ---------------- layer-2 aggregation + bias + log_softmax (2 nodes/wave) ----------------

__global__ void agg2_lsm(const int* __restrict__ rowptr, const int* __restrict__ deg,
                         const int* __restrict__ esrc, const float* __restrict__ dinv,
                         const ushort* __restrict__ h2b, const float* __restrict__ b2,
                         float* __restrict__ out) {
    int t = threadIdx.x;
    int w = t >> 6, lane = t & 63;
    int half = lane >> 5, l = lane & 31;
    int v = blockIdx.x * 8 + w * 2 + half;   // grid: v < N_NODES always
    int beg = rowptr[v], d = deg[v];
    float dv = dinv[v];
    float ax = 0.f, ay = 0.f;
    if (l < 20) {
        uint hv = *(const uint*)(h2b + (size_t)v * H2S + l * 2);
        ax = bflo(hv) * dv * dv;
        ay = bfhi(hv) * dv * dv;
    }
    int e_l = (l < d) ? esrc[beg + l] : 0;
    float w_l = (l < d) ? dinv[e_l] : 0.f;
    int dm = min(d, 32);
    int base = half * 32;
    int i = 0;
    for (; i + 4 <= dm; i += 4) {
        int s0 = __shfl(e_l, base + i + 0, 64);
        int s1 = __shfl(e_l, base + i + 1, 64);
        int s2 = __shfl(e_l, base + i + 2, 64);
        int s3 = __shfl(e_l, base + i + 3, 64);
        float g0 = __shfl(w_l, base + i + 0, 64) * dv;
        float g1 = __shfl(w_l, base + i + 1, 64) * dv;
        float g2 = __shfl(w_l, base + i + 2, 64) * dv;
        float g3 = __shfl(w_l, base + i + 3, 64) * dv;
        if (l < 20) {
            uint h0 = *(const uint*)(h2b + (size_t)s0 * H2S + l * 2);
            uint h1 = *(const uint*)(h2b + (size_t)s1 * H2S + l * 2);
            uint h2 = *(const uint*)(h2b + (size_t)s2 * H2S + l * 2);
            uint h3 = *(const uint*)(h2b + (size_t)s3 * H2S + l * 2);
            ax = fmaf(bflo(h0), g0, ax); ay = fmaf(bfhi(h0), g0, ay);
            ax = fmaf(bflo(h1), g1, ax); ay = fmaf(bfhi(h1), g1, ay);
            ax = fmaf(bflo(h2), g2, ax); ay = fmaf(bfhi(h2), g2, ay);
            ax = fmaf(bflo(h3), g3, ax); ay = fmaf(bfhi(h3), g3, ay);
        }
    }
    for (; i < dm; ++i) {
        int s = __shfl(e_l, base + i, 64);
        float g = __shfl(w_l, base + i, 64) * dv;
        if (l < 20) {
            uint hs = *(const uint*)(h2b + (size_t)s * H2S + l * 2);
            ax = fmaf(bflo(hs), g, ax);
            ay = fmaf(bfhi(hs), g, ay);
        }
    }
    for (i = 32; i < d; ++i) {               // rare tail
        int s = esrc[beg + i];
        float g = dinv[s] * dv;
        if (l < 20) {
            uint hs = *(const uint*)(h2b + (size_t)s * H2S + l * 2);
            ax = fmaf(bflo(hs), g, ax);
            ay = fmaf(bfhi(hs), g, ay);
        }
    }
    if (l < 20) {
        float2 bb = ((const float2*)b2)[l];
        ax += bb.x; ay += bb.y;
    }
    float m = (l < 20) ? fmaxf(ax, ay) : -INFINITY;
#pragma unroll
    for (int off = 16; off; off >>= 1) m = fmaxf(m, __shfl_xor(m, off, 64));
    float e = (l < 20) ? (expf(ax - m) + expf(ay - m)) : 0.f;
#pragma unroll
    for (int off = 16; off; off >>= 1) e += __shfl_xor(e, off, 64);
    float ls = logf(e);
    if (l < 20) {
        float2 o;
        o.x = ax - m - ls;
        o.y = ay - m - ls;
        ((float2*)(out + (size_t)v * N_CLASSES))[l] = o;
    }
}

// ---------------- launch ----------------

extern "C" void kernel_launch(void* const* d_in, const int* in_sizes, int n_in,
                              void* d_out, int out_size, void* d_ws, size_t ws_size,
                              hipStream_t stream) {
    const float* x  = (const float*)d_in[0];
    const int*   ei = (const int*)d_in[1];
    const float* W1 = (const float*)d_in[2];
    const float* b1 = (const float*)d_in[3];
    const float* W2 = (const float*)d_in[4];
    const float* b2 = (const float*)d_in[5];
    const int* src = ei;
    const int* dst = ei + N_EDGES;
    float* out = (float*)d_out;

    char* ws = (char*)d_ws;
    size_t off = 0;
    auto alloc = [&](size_t bytes) {
        void* p = ws + off;
        off += (bytes + 255) & ~(size_t)255;
        return p;
    };
    int*    deg    = (int*)alloc((size_t)N_NODES * 4);
    float*  dinv   = (float*)alloc((size_t)N_NODES * 4);
    int*    histT  = (int*)alloc((size_t)NBUCKET * 256 * 4);
    int*    incl   = (int*)alloc((size_t)NBUCKET * 256 * 4);
    int*    rowptr = (int*)alloc((size_t)N_NODES * 4);
    int*    bsum   = (int*)alloc((size_t)256 * 4);
    uint*   ebuf   = (uint*)alloc((size_t)N_EDGES * 4);
    int*    esrc   = (int*)alloc((size_t)N_EDGES * 4);
    ushort* Bp1    = (ushort*)alloc((size_t)32768 * 2);
    ushort* h1b    = (ushort*)alloc((size_t)ROWS_PAD * HIDDEN * 2);
    ushort* h2b    = (ushort*)alloc((size_t)ROWS_PAD * H2S * 2);

    // --- preprocessing: 4 kernels ---
    hist_repack<<<256, 256, 0, stream>>>(dst, histT, W1, Bp1);
    scan_a<<<NBUCKET, 256, 0, stream>>>(histT, incl, bsum);
    partition_k<<<256, 256, 0, stream>>>(src, dst, incl, histT, bsum, ebuf);
    bucket_csr<<<NBUCKET, 256, 0, stream>>>(ebuf, bsum, deg, dinv, rowptr, esrc);

    // --- model: 3 kernels ---
    gemm1_mfma<<<ROWS_PAD / 64, 256, 0, stream>>>(x, Bp1, h1b);
    agg1_gemm2<<<N_NODES / 4, 256, 0, stream>>>(rowptr, deg, esrc, dinv, h1b, b1, W2, h2b);
    agg2_lsm<<<N_NODES / 8, 256, 0, stream>>>(rowptr, deg, esrc, dinv, h2b, b2, out);
}

// Round 9
// 208.310 us; speedup vs baseline: 1.0979x; 1.0979x over previous
//
#include <hip/hip_runtime.h>
#include <cstdint>

#define N_NODES 50000
#define N_EDGES 800000
#define N_FEAT 256
#define HIDDEN 128
#define N_CLASSES 40
#define NBUCKET 196         // dst >> 8
#define EPB 3125            // edges per partition block (256 * 3125 = 800000)
#define BCAP 8192           // bucket capacity in ebuf (max count ~4400 = 4096+4*sigma)
#define ROWS_PAD 50048      // 782 * 64
#define H2S 64              // h2 row stride (ushorts) = 128 B aligned

typedef __attribute__((ext_vector_type(8))) short bf16x8;
typedef __attribute__((ext_vector_type(4))) float f32x4;

__device__ inline ushort f2bf(float f) {
    union { float f; uint u; } v; v.f = f;
    uint u = v.u;
    u += 0x7fff + ((u >> 16) & 1);   // round-to-nearest-even
    return (ushort)(u >> 16);
}
__device__ inline float bflo(uint u) {
    union { uint u; float f; } v; v.u = u << 16; return v.f;
}
__device__ inline float bfhi(uint u) {
    union { uint u; float f; } v; v.u = u & 0xffff0000u; return v.f;
}

// ---------------- 1) partition edges into fixed-capacity buckets + W1 repack ----------------
// LDS histogram -> ONE global atomic per (bucket, block) claims a region -> place.
// cursor[196] pre-zeroed by hipMemsetAsync; ends holding per-bucket edge counts.

__global__ __launch_bounds__(256) void partition_repack(
        const int* __restrict__ src, const int* __restrict__ dst,
        int* __restrict__ cursor, uint* __restrict__ ebuf,
        const float* __restrict__ W1, ushort* __restrict__ Bp1) {
    __shared__ int h[NBUCKET];
    __shared__ int base[NBUCKET];
    __shared__ int cur[NBUCKET];
    int blk = blockIdx.x, t = threadIdx.x;
    int gid = blk * 256 + t;
    if (gid < 32768) {       // W1 repack into MFMA B-frag order
        int j = gid & 7, lane = (gid >> 3) & 63, kt = (gid >> 9) & 7, nt = gid >> 12;
        int k = kt * 32 + (lane >> 4) * 8 + j;
        int n = nt * 16 + (lane & 15);
        Bp1[gid] = f2bf(W1[k * HIDDEN + n]);
    }
    if (t < NBUCKET) { h[t] = 0; cur[t] = 0; }
    __syncthreads();
    int eb = blk * EPB;
    for (int i = t; i < EPB; i += 256)
        atomicAdd(&h[dst[eb + i] >> 8], 1);
    __syncthreads();
    if (t < NBUCKET)
        base[t] = (h[t] > 0) ? atomicAdd(&cursor[t], h[t]) : 0;
    __syncthreads();
    for (int i = t; i < EPB; i += 256) {
        int d = dst[eb + i], sv = src[eb + i];
        int bk = d >> 8;
        int p = base[bk] + atomicAdd(&cur[bk], 1);
        ebuf[bk * BCAP + p] = ((uint)d << 16) | (uint)sv;
    }
}

// ---------------- 2) per-bucket: degree + dinv + rowptr + CSR fill ----------------
// global bucket CSR start = LDS prefix-scan over cursor[196].

__global__ __launch_bounds__(256) void bucket_csr(
        const uint* __restrict__ ebuf, const int* __restrict__ cursor,
        int* __restrict__ deg, float* __restrict__ dinv,
        int* __restrict__ rowptr, int* __restrict__ esrc) {
    __shared__ int s[256];
    __shared__ int cnt[256];
    __shared__ int exc[256];
    __shared__ int cur[256];
    int b = blockIdx.x, t = threadIdx.x;
    s[t] = (t < NBUCKET) ? cursor[t] : 0;
    __syncthreads();
    for (int off = 1; off < 256; off <<= 1) {
        int t2 = 0;
        if (t >= off) t2 = s[t - off];
        __syncthreads();
        s[t] += t2;
        __syncthreads();
    }
    int beg = (b > 0) ? s[b - 1] : 0;      // CSR start of bucket b
    int ecnt = s[b] - beg;                 // edges in bucket b
    __syncthreads();
    cnt[t] = 0;
    cur[t] = 0;
    __syncthreads();
    const uint* eb = ebuf + (size_t)b * BCAP;
    for (int i = t; i < ecnt; i += 256)
        atomicAdd(&cnt[(eb[i] >> 16) & 255], 1);
    __syncthreads();
    int d = cnt[t];
    s[t] = d;
    __syncthreads();
    for (int off = 1; off < 256; off <<= 1) {
        int t2 = 0;
        if (t >= off) t2 = s[t - off];
        __syncthreads();
        s[t] += t2;
        __syncthreads();
    }
    exc[t] = s[t] - d;
    int node = b * 256 + t;
    if (node < N_NODES) {
        deg[node] = d;
        dinv[node] = rsqrtf((float)(d + 1));   // +1 self-loop
        rowptr[node] = beg + exc[t];
    }
    __syncthreads();
    for (int i = t; i < ecnt; i += 256) {
        uint u = eb[i];
        int dl = (int)(u >> 16) & 255;
        int pos = beg + exc[dl] + atomicAdd(&cur[dl], 1);
        esrc[pos] = (int)(u & 0xffffu);
    }
}

// ---------------- GEMM1: h1b[N,128] = bf16(x[N,256]) @ W1  (MFMA) ----------------

#define XS_STRIDE 264   // 256 + 8 bf16 pad

__global__ __launch_bounds__(256) void gemm1_mfma(const float* __restrict__ x,
                                                  const ushort* __restrict__ Bp,
                                                  ushort* __restrict__ h1b) {
    __shared__ ushort xs[64 * XS_STRIDE];   // 33792 B
    int t = threadIdx.x;
    int row0 = blockIdx.x * 64;
#pragma unroll
    for (int i = 0; i < 16; ++i) {
        int idx = t + i * 256;
        int r = idx >> 6, kg = idx & 63;
        int row = row0 + r;
        float4 v = make_float4(0.f, 0.f, 0.f, 0.f);
        if (row < N_NODES) v = *(const float4*)(x + (size_t)row * N_FEAT + kg * 4);
        ushort4 u;
        u.x = f2bf(v.x); u.y = f2bf(v.y); u.z = f2bf(v.z); u.w = f2bf(v.w);
        *(ushort4*)(&xs[r * XS_STRIDE + kg * 4]) = u;
    }
    __syncthreads();
    int lane = t & 63, w = t >> 6;
    int r = lane & 15, q = lane >> 4;
    f32x4 acc[8] = {};
    for (int kt = 0; kt < 8; ++kt) {
        bf16x8 a = *(const bf16x8*)(&xs[(w * 16 + r) * XS_STRIDE + kt * 32 + q * 8]);
#pragma unroll
        for (int nt = 0; nt < 8; ++nt) {
            bf16x8 b = *(const bf16x8*)(Bp + (((nt * 8 + kt) * 64) + lane) * 8);
            acc[nt] = __builtin_amdgcn_mfma_f32_16x16x32_bf16(a, b, acc[nt], 0, 0, 0);
        }
    }
#pragma unroll
    for (int nt = 0; nt < 8; ++nt) {
        int col = nt * 16 + r;
#pragma unroll
        for (int reg = 0; reg < 4; ++reg) {
            int row = row0 + w * 16 + q * 4 + reg;
            if (row < N_NODES) h1b[(size_t)row * HIDDEN + col] = f2bf(acc[nt][reg]);
        }
    }
}

// ---------------- layer-1 aggregation: quarter-wave edges, uint4 loads ----------------
// wave = 1 node; quarter q (16 lanes) owns edge i+q; lane l<16 covers feats 8l..8l+7.

__global__ __launch_bounds__(256) void agg1_g(
        const int* __restrict__ rowptr, const int* __restrict__ deg,
        const int* __restrict__ esrc, const float* __restrict__ dinv,
        const ushort* __restrict__ h1b, const float* __restrict__ b1,
        ushort* __restrict__ hagb) {
    int w = threadIdx.x >> 6, lane = threadIdx.x & 63;
    int v = blockIdx.x * 4 + w;              // grid 12500 -> v < 50000
    int q = lane >> 4, l = lane & 15;
    int beg = rowptr[v], d = deg[v];
    float dv = dinv[v];
    float a0 = 0.f, a1 = 0.f, a2 = 0.f, a3 = 0.f;
    float a4 = 0.f, a5 = 0.f, a6 = 0.f, a7 = 0.f;
    if (q == 0) {                            // self-loop counted once
        uint4 hv = *(const uint4*)(h1b + (size_t)v * HIDDEN + l * 8);
        float dd = dv * dv;
        a0 = bflo(hv.x) * dd; a1 = bfhi(hv.x) * dd;
        a2 = bflo(hv.y) * dd; a3 = bfhi(hv.y) * dd;
        a4 = bflo(hv.z) * dd; a5 = bfhi(hv.z) * dd;
        a6 = bflo(hv.w) * dd; a7 = bfhi(hv.w) * dd;
    }
    int e_l = (lane < d) ? esrc[beg + lane] : 0;
    float w_l = (lane < d) ? dinv[e_l] : 0.f;   // 0 weight: invalid edges vanish
    int dm = min(d, 64);
    int i = 0;
    for (; i + 8 <= dm; i += 8) {            // 8 edges per iter, 2 loads in flight
        int s0 = __shfl(e_l, i + q, 64);
        int s1 = __shfl(e_l, i + 4 + q, 64);
        float g0 = __shfl(w_l, i + q, 64) * dv;
        float g1 = __shfl(w_l, i + 4 + q, 64) * dv;
        uint4 h0 = *(const uint4*)(h1b + (size_t)s0 * HIDDEN + l * 8);
        uint4 h1 = *(const uint4*)(h1b + (size_t)s1 * HIDDEN + l * 8);
        a0 = fmaf(bflo(h0.x), g0, a0); a1 = fmaf(bfhi(h0.x), g0, a1);
        a2 = fmaf(bflo(h0.y), g0, a2); a3 = fmaf(bfhi(h0.y), g0, a3);
        a4 = fmaf(bflo(h0.z), g0, a4); a5 = fmaf(bfhi(h0.z), g0, a5);
        a6 = fmaf(bflo(h0.w), g0, a6); a7 = fmaf(bfhi(h0.w), g0, a7);
        a0 = fmaf(bflo(h1.x), g1, a0); a1 = fmaf(bfhi(h1.x), g1, a1);
        a2 = fmaf(bflo(h1.y), g1, a2); a3 = fmaf(bfhi(h1.y), g1, a3);
        a4 = fmaf(bflo(h1.z), g1, a4); a5 = fmaf(bfhi(h1.z), g1, a5);
        a6 = fmaf(bflo(h1.w), g1, a6); a7 = fmaf(bfhi(h1.w), g1, a7);
    }
    for (; i < dm; i += 4) {                 // tail: clamp shfl idx, mask weight
        int idx = i + q;
        int cl = idx & 63;
        int s0 = __shfl(e_l, cl, 64);
        float g0 = __shfl(w_l, cl, 64) * dv;
        if (idx >= dm) g0 = 0.f;
        uint4 h0 = *(const uint4*)(h1b + (size_t)s0 * HIDDEN + l * 8);
        a0 = fmaf(bflo(h0.x), g0, a0); a1 = fmaf(bfhi(h0.x), g0, a1);
        a2 = fmaf(bflo(h0.y), g0, a2); a3 = fmaf(bfhi(h0.y), g0, a3);
        a4 = fmaf(bflo(h0.z), g0, a4); a5 = fmaf(bfhi(h0.z), g0, a5);
        a6 = fmaf(bflo(h0.w), g0, a6); a7 = fmaf(bfhi(h0.w), g0, a7);
    }
    for (int j = 64 + q; j < d; j += 4) {    // rare deg>64 tail
        int s = esrc[beg + j];
        float g = dinv[s] * dv;
        uint4 hs = *(const uint4*)(h1b + (size_t)s * HIDDEN + l * 8);
        a0 = fmaf(bflo(hs.x), g, a0); a1 = fmaf(bfhi(hs.x), g, a1);
        a2 = fmaf(bflo(hs.y), g, a2); a3 = fmaf(bfhi(hs.y), g, a3);
        a4 = fmaf(bflo(hs.z), g, a4); a5 = fmaf(bfhi(hs.z), g, a5);
        a6 = fmaf(bflo(hs.w), g, a6); a7 = fmaf(bfhi(hs.w), g, a7);
    }
    // fold quarters (0<-1, 2<-3, then 0<-2)
    a0 += __shfl_xor(a0, 16, 64); a0 += __shfl_xor(a0, 32, 64);
    a1 += __shfl_xor(a1, 16, 64); a1 += __shfl_xor(a1, 32, 64);
    a2 += __shfl_xor(a2, 16, 64); a2 += __shfl_xor(a2, 32, 64);
    a3 += __shfl_xor(a3, 16, 64); a3 += __shfl_xor(a3, 32, 64);
    a4 += __shfl_xor(a4, 16, 64); a4 += __shfl_xor(a4, 32, 64);
    a5 += __shfl_xor(a5, 16, 64); a5 += __shfl_xor(a5, 32, 64);
    a6 += __shfl_xor(a6, 16, 64); a6 += __shfl_xor(a6, 32, 64);
    a7 += __shfl_xor(a7, 16, 64); a7 += __shfl_xor(a7, 32, 64);
    if (q == 0) {
        float4 bb0 = ((const float4*)b1)[l * 2];
        float4 bb1 = ((const float4*)b1)[l * 2 + 1];
        a0 += bb0.x; a1 += bb0.y; a2 += bb0.z; a3 += bb0.w;
        a4 += bb1.x; a5 += bb1.y; a6 += bb1.z; a7 += bb1.w;
        a0 = a0 > 0.f ? a0 : 0.f;  a1 = a1 > 0.f ? a1 : 0.f;
        a2 = a2 > 0.f ? a2 : 0.f;  a3 = a3 > 0.f ? a3 : 0.f;
        a4 = a4 > 0.f ? a4 : 0.f;  a5 = a5 > 0.f ? a5 : 0.f;
        a6 = a6 > 0.f ? a6 : 0.f;  a7 = a7 > 0.f ? a7 : 0.f;
        uint4 o;
        o.x = ((uint)f2bf(a1) << 16) | (uint)f2bf(a0);
        o.y = ((uint)f2bf(a3) << 16) | (uint)f2bf(a2);
        o.z = ((uint)f2bf(a5) << 16) | (uint)f2bf(a4);
        o.w = ((uint)f2bf(a7) << 16) | (uint)f2bf(a6);
        *(uint4*)(hagb + (size_t)v * HIDDEN + l * 8) = o;
    }
}

// ---------------- GEMM2: h2b[N,H2S] = hagb[N,128] @ W2  (MFMA, padded rows) ----------------

__global__ void repack_W2(const float* __restrict__ W, ushort* __restrict__ Bp) {
    int idx = blockIdx.x * 256 + threadIdx.x;          // 3 nt * 4 kt * 64 * 8 = 6144
    if (idx >= 6144) return;
    int j = idx & 7, lane = (idx >> 3) & 63, kt = (idx >> 9) & 3, nt = idx >> 11;
    int k = kt * 32 + (lane >> 4) * 8 + j;
    int n = nt * 16 + (lane & 15);
    Bp[idx] = (n < N_CLASSES) ? f2bf(W[k * N_CLASSES + n]) : (ushort)0;
}

__global__ __launch_bounds__(256) void gemm2_mfma(const ushort* __restrict__ hagb,
                                                  const ushort* __restrict__ Bp,
                                                  ushort* __restrict__ h2b) {
    int t = threadIdx.x;
    int lane = t & 63, w = t >> 6;
    int r = lane & 15, q = lane >> 4;
    int row0 = blockIdx.x * 64;
    int arow = row0 + w * 16 + r;            // rows < ROWS_PAD, buffer padded
    f32x4 acc[3] = {};
    for (int kt = 0; kt < 4; ++kt) {
        bf16x8 a = *(const bf16x8*)(hagb + (size_t)arow * HIDDEN + kt * 32 + q * 8);
#pragma unroll
        for (int nt = 0; nt < 3; ++nt) {
            bf16x8 b = *(const bf16x8*)(Bp + (((nt * 4 + kt) * 64) + lane) * 8);
            acc[nt] = __builtin_amdgcn_mfma_f32_16x16x32_bf16(a, b, acc[nt], 0, 0, 0);
        }
    }
#pragma unroll
    for (int nt = 0; nt < 3; ++nt) {
        int col = nt * 16 + r;
        if (col >= N_CLASSES) continue;
#pragma unroll
        for (int reg = 0; reg < 4; ++reg) {
            int row = row0 + w * 16 + q * 4 + reg;
            if (row < N_NODES) h2b[(size_t)row * H2S + col] = f2bf(acc[nt][reg]);
        }
    }
}

// ---------------- layer-2 aggregation + bias + log_softmax ----------------
// wave = 1 node; 3 groups of 20 lanes own edges i+g (lanes 60-63 idle); lane l covers feats 2l,2l+1.

__global__ __launch_bounds__(256) void agg2_lsm(
        const int* __restrict__ rowptr, const int* __restrict__ deg,
        const int* __restrict__ esrc, const float* __restrict__ dinv,
        const ushort* __restrict__ h2b, const float* __restrict__ b2,
        float* __restrict__ out) {
    int w = threadIdx.x >> 6, lane = threadIdx.x & 63;
    int v = blockIdx.x * 4 + w;              // grid 12500 -> v < 50000
    int g3 = lane / 20;                      // 0..3 (3 = idle tail)
    int l = lane - g3 * 20;
    bool act = g3 < 3;
    int beg = rowptr[v], d = deg[v];
    float dv = dinv[v];
    float ax = 0.f, ay = 0.f;
    if (lane < 20) {                         // self-loop on group 0
        uint hv = *(const uint*)(h2b + (size_t)v * H2S + l * 2);
        ax = bflo(hv) * dv * dv;
        ay = bfhi(hv) * dv * dv;
    }
    int e_l = (lane < d) ? esrc[beg + lane] : 0;
    float w_l = (lane < d) ? dinv[e_l] : 0.f;
    int dm = min(d, 64);
    int i = 0;
    for (; i + 6 <= dm; i += 6) {            // 6 edges per iter, 2 loads in flight
        int s0 = __shfl(e_l, (i + g3) & 63, 64);
        int s1 = __shfl(e_l, (i + 3 + g3) & 63, 64);
        float g0 = __shfl(w_l, (i + g3) & 63, 64) * dv;
        float g1 = __shfl(w_l, (i + 3 + g3) & 63, 64) * dv;
        if (!act) { g0 = 0.f; g1 = 0.f; }
        uint h0 = *(const uint*)(h2b + (size_t)s0 * H2S + l * 2);
        uint h1 = *(const uint*)(h2b + (size_t)s1 * H2S + l * 2);
        ax = fmaf(bflo(h0), g0, ax); ay = fmaf(bfhi(h0), g0, ay);
        ax = fmaf(bflo(h1), g1, ax); ay = fmaf(bfhi(h1), g1, ay);
    }
    for (; i < dm; i += 3) {
        int idx = i + g3;
        int s0 = __shfl(e_l, idx & 63, 64);
        float g0 = __shfl(w_l, idx & 63, 64) * dv;
        if (!act || idx >= dm) g0 = 0.f;
        uint h0 = *(const uint*)(h2b + (size_t)s0 * H2S + l * 2);
        ax = fmaf(bflo(h0), g0, ax); ay = fmaf(bfhi(h0), g0, ay);
    }
    for (int j = 64 + g3; j < d; j += 3) {   // rare deg>64 tail
        if (act) {
            int s = esrc[beg + j];
            float g = dinv[s] * dv;
            uint hs = *(const uint*)(h2b + (size_t)s * H2S + l * 2);
            ax = fmaf(bflo(hs), g, ax);
            ay = fmaf(bfhi(hs), g, ay);
        }
    }
    // fold groups 1,2 into group 0
    float fx1 = __shfl(ax, (lane + 20) & 63, 64);
    float fy1 = __shfl(ay, (lane + 20) & 63, 64);
    float fx2 = __shfl(ax, (lane + 40) & 63, 64);
    float fy2 = __shfl(ay, (lane + 40) & 63, 64);
    if (lane < 20) {
        ax += fx1 + fx2;
        ay += fy1 + fy2;
        float2 bb = ((const float2*)b2)[l];
        ax += bb.x; ay += bb.y;
    }
    float m = (lane < 20) ? fmaxf(ax, ay) : -INFINITY;
#pragma unroll
    for (int off = 32; off; off >>= 1) m = fmaxf(m, __shfl_xor(m, off, 64));
    float e = (lane < 20) ? (expf(ax - m) + expf(ay - m)) : 0.f;
#pragma unroll
    for (int off = 32; off; off >>= 1) e += __shfl_xor(e, off, 64);
    float ls = logf(e);
    if (lane < 20) {
        float2 o;
        o.x = ax - m - ls;
        o.y = ay - m - ls;
        ((float2*)(out + (size_t)v * N_CLASSES))[l] = o;
    }
}

// ---------------- launch ----------------

extern "C" void kernel_launch(void* const* d_in, const int* in_sizes, int n_in,
                              void* d_out, int out_size, void* d_ws, size_t ws_size,
                              hipStream_t stream) {
    const float* x  = (const float*)d_in[0];
    const int*   ei = (const int*)d_in[1];
    const float* W1 = (const float*)d_in[2];
    const float* b1 = (const float*)d_in[3];
    const float* W2 = (const float*)d_in[4];
    const float* b2 = (const float*)d_in[5];
    const int* src = ei;
    const int* dst = ei + N_EDGES;
    float* out = (float*)d_out;

    char* ws = (char*)d_ws;
    size_t off = 0;
    auto alloc = [&](size_t bytes) {
        void* p = ws + off;
        off += (bytes + 255) & ~(size_t)255;
        return p;
    };
    int*    cursor = (int*)alloc((size_t)NBUCKET * 4);
    int*    deg    = (int*)alloc((size_t)N_NODES * 4);
    float*  dinv   = (float*)alloc((size_t)N_NODES * 4);
    int*    rowptr = (int*)alloc((size_t)N_NODES * 4);
    uint*   ebuf   = (uint*)alloc((size_t)NBUCKET * BCAP * 4);
    int*    esrc   = (int*)alloc((size_t)N_EDGES * 4);
    ushort* Bp1    = (ushort*)alloc((size_t)32768 * 2);
    ushort* Bp2    = (ushort*)alloc((size_t)6144 * 2);
    ushort* h1b    = (ushort*)alloc((size_t)ROWS_PAD * HIDDEN * 2);
    ushort* hagb   = (ushort*)alloc((size_t)ROWS_PAD * HIDDEN * 2);
    ushort* h2b    = (ushort*)alloc((size_t)ROWS_PAD * H2S * 2);

    // --- preprocessing: memset + 2 kernels ---
    hipMemsetAsync(cursor, 0, (size_t)NBUCKET * 4, stream);
    partition_repack<<<256, 256, 0, stream>>>(src, dst, cursor, ebuf, W1, Bp1);
    bucket_csr<<<NBUCKET, 256, 0, stream>>>(ebuf, cursor, deg, dinv, rowptr, esrc);

    // --- model: 5 kernels ---
    repack_W2<<<24, 256, 0, stream>>>(W2, Bp2);
    gemm1_mfma<<<ROWS_PAD / 64, 256, 0, stream>>>(x, Bp1, h1b);
    agg1_g<<<N_NODES / 4, 256, 0, stream>>>(rowptr, deg, esrc, dinv, h1b, b1, hagb);
    gemm2_mfma<<<ROWS_PAD / 64, 256, 0, stream>>>(hagb, Bp2, h2b);
    agg2_lsm<<<N_NODES / 4, 256, 0, stream>>>(rowptr, deg, esrc, dinv, h2b, b2, out);
}

// Round 10
// 198.974 us; speedup vs baseline: 1.1494x; 1.0469x over previous
//
#include <hip/hip_runtime.h>
#include <hip/hip_fp16.h>
#include <cstdint>

#define N_NODES 50000
#define N_EDGES 800000
#define N_FEAT 256
#define HIDDEN 128
#define N_CLASSES 40
#define NBUCKET 196         // dst >> 8
#define EPB 3125            // edges per partition block (256 * 3125 = 800000)
#define BCAP 8192           // bucket capacity in ebuf (max count ~4400)
#define ROWS_PAD 50048      // 782 * 64
#define H2S 64              // h2 row stride (halves) = 128 B aligned

typedef _Float16 half8 __attribute__((ext_vector_type(8)));
typedef __attribute__((ext_vector_type(4))) float f32x4;

__device__ inline ushort f2h(float f) {
    return __half_as_ushort(__float2half_rn(f));
}
__device__ inline __half2 u2h2(uint u) {
    union { uint u; __half2 h; } v; v.u = u; return v.h;
}

// ---------------- 0) setup: W2 repack (f16 B-frags) + zero bucket cursors ----------------

__global__ void setup_k(const float* __restrict__ W2, ushort* __restrict__ Bp2,
                        int* __restrict__ cursor) {
    int blk = blockIdx.x, t = threadIdx.x;
    if (blk < 24) {
        int idx = blk * 256 + t;               // 3 nt * 4 kt * 64 * 8 = 6144
        int j = idx & 7, lane = (idx >> 3) & 63, kt = (idx >> 9) & 3, nt = idx >> 11;
        int k = kt * 32 + (lane >> 4) * 8 + j;
        int n = nt * 16 + (lane & 15);
        Bp2[idx] = (n < N_CLASSES) ? f2h(W2[k * N_CLASSES + n]) : (ushort)0;
    } else {
        if (t < NBUCKET) cursor[t] = 0;
    }
}

// ---------------- 1) partition edges into fixed-capacity buckets + W1 repack ----------------

__global__ __launch_bounds__(256) void partition_repack(
        const int* __restrict__ src, const int* __restrict__ dst,
        int* __restrict__ cursor, uint* __restrict__ ebuf,
        const float* __restrict__ W1, ushort* __restrict__ Bp1) {
    __shared__ int h[NBUCKET];
    __shared__ int base[NBUCKET];
    __shared__ int cur[NBUCKET];
    int blk = blockIdx.x, t = threadIdx.x;
    int gid = blk * 256 + t;
    if (gid < 32768) {       // W1 repack into MFMA B-frag order (f16)
        int j = gid & 7, lane = (gid >> 3) & 63, kt = (gid >> 9) & 7, nt = gid >> 12;
        int k = kt * 32 + (lane >> 4) * 8 + j;
        int n = nt * 16 + (lane & 15);
        Bp1[gid] = f2h(W1[k * HIDDEN + n]);
    }
    if (t < NBUCKET) { h[t] = 0; cur[t] = 0; }
    __syncthreads();
    int eb = blk * EPB;
    for (int i = t; i < EPB; i += 256)
        atomicAdd(&h[dst[eb + i] >> 8], 1);
    __syncthreads();
    if (t < NBUCKET)
        base[t] = (h[t] > 0) ? atomicAdd(&cursor[t], h[t]) : 0;
    __syncthreads();
    for (int i = t; i < EPB; i += 256) {
        int d = dst[eb + i], sv = src[eb + i];
        int bk = d >> 8;
        int p = base[bk] + atomicAdd(&cur[bk], 1);
        ebuf[bk * BCAP + p] = ((uint)d << 16) | (uint)sv;
    }
}

// ---------------- 2) per-bucket: degree + dinv + rowptr + CSR fill ----------------

__global__ __launch_bounds__(256) void bucket_csr(
        const uint* __restrict__ ebuf, const int* __restrict__ cursor,
        int* __restrict__ deg, float* __restrict__ dinv,
        int* __restrict__ rowptr, int* __restrict__ esrc) {
    __shared__ int s[256];
    __shared__ int cnt[256];
    __shared__ int exc[256];
    __shared__ int cur[256];
    int b = blockIdx.x, t = threadIdx.x;
    s[t] = (t < NBUCKET) ? cursor[t] : 0;
    __syncthreads();
    for (int off = 1; off < 256; off <<= 1) {
        int t2 = 0;
        if (t >= off) t2 = s[t - off];
        __syncthreads();
        s[t] += t2;
        __syncthreads();
    }
    int beg = (b > 0) ? s[b - 1] : 0;      // CSR start of bucket b
    int ecnt = s[b] - beg;                 // edges in bucket b
    __syncthreads();
    cnt[t] = 0;
    cur[t] = 0;
    __syncthreads();
    const uint* eb = ebuf + (size_t)b * BCAP;
    for (int i = t; i < ecnt; i += 256)
        atomicAdd(&cnt[(eb[i] >> 16) & 255], 1);
    __syncthreads();
    int d = cnt[t];
    s[t] = d;
    __syncthreads();
    for (int off = 1; off < 256; off <<= 1) {
        int t2 = 0;
        if (t >= off) t2 = s[t - off];
        __syncthreads();
        s[t] += t2;
        __syncthreads();
    }
    exc[t] = s[t] - d;
    int node = b * 256 + t;
    if (node < N_NODES) {
        deg[node] = d;
        dinv[node] = rsqrtf((float)(d + 1));   // +1 self-loop
        rowptr[node] = beg + exc[t];
    }
    __syncthreads();
    for (int i = t; i < ecnt; i += 256) {
        uint u = eb[i];
        int dl = (int)(u >> 16) & 255;
        int pos = beg + exc[dl] + atomicAdd(&cur[dl], 1);
        esrc[pos] = (int)(u & 0xffffu);
    }
}

// ---------------- GEMM1: h1h[N,128] = f16(x[N,256]) @ W1  (MFMA f16) ----------------

#define XS_STRIDE 264   // 256 + 8 f16 pad

__global__ __launch_bounds__(256) void gemm1_mfma(const float* __restrict__ x,
                                                  const ushort* __restrict__ Bp,
                                                  ushort* __restrict__ h1h) {
    __shared__ ushort xs[64 * XS_STRIDE];   // 33792 B
    int t = threadIdx.x;
    int row0 = blockIdx.x * 64;
#pragma unroll
    for (int i = 0; i < 16; ++i) {
        int idx = t + i * 256;
        int r = idx >> 6, kg = idx & 63;
        int row = row0 + r;
        float4 v = make_float4(0.f, 0.f, 0.f, 0.f);
        if (row < N_NODES) v = *(const float4*)(x + (size_t)row * N_FEAT + kg * 4);
        ushort4 u;
        u.x = f2h(v.x); u.y = f2h(v.y); u.z = f2h(v.z); u.w = f2h(v.w);
        *(ushort4*)(&xs[r * XS_STRIDE + kg * 4]) = u;
    }
    __syncthreads();
    int lane = t & 63, w = t >> 6;
    int r = lane & 15, q = lane >> 4;
    f32x4 acc[8] = {};
    for (int kt = 0; kt < 8; ++kt) {
        half8 a = *(const half8*)(&xs[(w * 16 + r) * XS_STRIDE + kt * 32 + q * 8]);
#pragma unroll
        for (int nt = 0; nt < 8; ++nt) {
            half8 b = *(const half8*)(Bp + (((nt * 8 + kt) * 64) + lane) * 8);
            acc[nt] = __builtin_amdgcn_mfma_f32_16x16x32_f16(a, b, acc[nt], 0, 0, 0);
        }
    }
#pragma unroll
    for (int nt = 0; nt < 8; ++nt) {
        int col = nt * 16 + r;
#pragma unroll
        for (int reg = 0; reg < 4; ++reg) {
            int row = row0 + w * 16 + q * 4 + reg;
            if (row < N_NODES) h1h[(size_t)row * HIDDEN + col] = f2h(acc[nt][reg]);
        }
    }
}

// ---------------- layer-1 aggregation: quarter-wave edges, uint4 loads, __hfma2 ----------------
// wave = 1 node; quarter q (16 lanes) owns edge i+q; lane l<16 covers feats 8l..8l+7.

__global__ __launch_bounds__(256) void agg1_g(
        const int* __restrict__ rowptr, const int* __restrict__ deg,
        const int* __restrict__ esrc, const float* __restrict__ dinv,
        const ushort* __restrict__ h1h, const float* __restrict__ b1,
        ushort* __restrict__ hagh) {
    int w = threadIdx.x >> 6, lane = threadIdx.x & 63;
    int v = blockIdx.x * 4 + w;              // grid 12500 -> v < 50000
    int q = lane >> 4, l = lane & 15;
    int beg = rowptr[v], d = deg[v];
    float dv = dinv[v];
    __half2 z = __float2half2_rn(0.f);
    __half2 c0 = z, c1 = z, c2 = z, c3 = z;  // chain A
    __half2 e0 = z, e1 = z, e2 = z, e3 = z;  // chain B
    if (q == 0) {                            // self-loop counted once
        uint4 hv = *(const uint4*)(h1h + (size_t)v * HIDDEN + l * 8);
        __half2 gs = __float2half2_rn(dv * dv);
        c0 = __hfma2(u2h2(hv.x), gs, c0);
        c1 = __hfma2(u2h2(hv.y), gs, c1);
        c2 = __hfma2(u2h2(hv.z), gs, c2);
        c3 = __hfma2(u2h2(hv.w), gs, c3);
    }
    int e_l = (lane < d) ? esrc[beg + lane] : 0;
    float w_l = (lane < d) ? dinv[e_l] : 0.f;   // 0 weight: invalid edges vanish
    int dm = min(d, 64);
    int i = 0;
    for (; i + 8 <= dm; i += 8) {            // 8 edges per iter, 2 loads in flight
        int s0 = __shfl(e_l, i + q, 64);
        int s1 = __shfl(e_l, i + 4 + q, 64);
        float g0 = __shfl(w_l, i + q, 64) * dv;
        float g1 = __shfl(w_l, i + 4 + q, 64) * dv;
        __half2 gh0 = __float2half2_rn(g0);
        __half2 gh1 = __float2half2_rn(g1);
        uint4 h0 = *(const uint4*)(h1h + (size_t)s0 * HIDDEN + l * 8);
        uint4 h1 = *(const uint4*)(h1h + (size_t)s1 * HIDDEN + l * 8);
        c0 = __hfma2(u2h2(h0.x), gh0, c0);
        c1 = __hfma2(u2h2(h0.y), gh0, c1);
        c2 = __hfma2(u2h2(h0.z), gh0, c2);
        c3 = __hfma2(u2h2(h0.w), gh0, c3);
        e0 = __hfma2(u2h2(h1.x), gh1, e0);
        e1 = __hfma2(u2h2(h1.y), gh1, e1);
        e2 = __hfma2(u2h2(h1.z), gh1, e2);
        e3 = __hfma2(u2h2(h1.w), gh1, e3);
    }
    for (; i < dm; i += 4) {                 // tail: clamp shfl idx, mask weight
        int idx = i + q;
        int cl = idx & 63;
        int s0 = __shfl(e_l, cl, 64);
        float g0 = __shfl(w_l, cl, 64) * dv;
        if (idx >= dm) g0 = 0.f;
        __half2 gh0 = __float2half2_rn(g0);
        uint4 h0 = *(const uint4*)(h1h + (size_t)s0 * HIDDEN + l * 8);
        c0 = __hfma2(u2h2(h0.x), gh0, c0);
        c1 = __hfma2(u2h2(h0.y), gh0, c1);
        c2 = __hfma2(u2h2(h0.z), gh0, c2);
        c3 = __hfma2(u2h2(h0.w), gh0, c3);
    }
    for (int j = 64 + q; j < d; j += 4) {    // rare deg>64 tail
        int s = esrc[beg + j];
        __half2 g = __float2half2_rn(dinv[s] * dv);
        uint4 hs = *(const uint4*)(h1h + (size_t)s * HIDDEN + l * 8);
        c0 = __hfma2(u2h2(hs.x), g, c0);
        c1 = __hfma2(u2h2(hs.y), g, c1);
        c2 = __hfma2(u2h2(hs.z), g, c2);
        c3 = __hfma2(u2h2(hs.w), g, c3);
    }
    // combine chains in fp32
    float2 f0 = __half22float2(c0), f1 = __half22float2(c1);
    float2 f2 = __half22float2(c2), f3 = __half22float2(c3);
    float2 g0 = __half22float2(e0), g1 = __half22float2(e1);
    float2 g2 = __half22float2(e2), g3 = __half22float2(e3);
    float a0 = f0.x + g0.x, a1 = f0.y + g0.y;
    float a2 = f1.x + g1.x, a3 = f1.y + g1.y;
    float a4 = f2.x + g2.x, a5 = f2.y + g2.y;
    float a6 = f3.x + g3.x, a7 = f3.y + g3.y;
    // fold quarters
    a0 += __shfl_xor(a0, 16, 64); a0 += __shfl_xor(a0, 32, 64);
    a1 += __shfl_xor(a1, 16, 64); a1 += __shfl_xor(a1, 32, 64);
    a2 += __shfl_xor(a2, 16, 64); a2 += __shfl_xor(a2, 32, 64);
    a3 += __shfl_xor(a3, 16, 64); a3 += __shfl_xor(a3, 32, 64);
    a4 += __shfl_xor(a4, 16, 64); a4 += __shfl_xor(a4, 32, 64);
    a5 += __shfl_xor(a5, 16, 64); a5 += __shfl_xor(a5, 32, 64);
    a6 += __shfl_xor(a6, 16, 64); a6 += __shfl_xor(a6, 32, 64);
    a7 += __shfl_xor(a7, 16, 64); a7 += __shfl_xor(a7, 32, 64);
    if (q == 0) {
        float4 bb0 = ((const float4*)b1)[l * 2];
        float4 bb1 = ((const float4*)b1)[l * 2 + 1];
        a0 += bb0.x; a1 += bb0.y; a2 += bb0.z; a3 += bb0.w;
        a4 += bb1.x; a5 += bb1.y; a6 += bb1.z; a7 += bb1.w;
        a0 = a0 > 0.f ? a0 : 0.f;  a1 = a1 > 0.f ? a1 : 0.f;
        a2 = a2 > 0.f ? a2 : 0.f;  a3 = a3 > 0.f ? a3 : 0.f;
        a4 = a4 > 0.f ? a4 : 0.f;  a5 = a5 > 0.f ? a5 : 0.f;
        a6 = a6 > 0.f ? a6 : 0.f;  a7 = a7 > 0.f ? a7 : 0.f;
        ushort4 o;   // pack pairs (lo = even feat)
        o.x = f2h(a0); // will store 8 halves as two ushort4
        uint4 ov;
        ov.x = ((uint)f2h(a1) << 16) | (uint)f2h(a0);
        ov.y = ((uint)f2h(a3) << 16) | (uint)f2h(a2);
        ov.z = ((uint)f2h(a5) << 16) | (uint)f2h(a4);
        ov.w = ((uint)f2h(a7) << 16) | (uint)f2h(a6);
        *(uint4*)(hagh + (size_t)v * HIDDEN + l * 8) = ov;
    }
}

// ---------------- GEMM2: h2h[N,H2S] = hagh[N,128] @ W2  (MFMA f16, padded rows) ----------------

__global__ __launch_bounds__(256) void gemm2_mfma(const ushort* __restrict__ hagh,
                                                  const ushort* __restrict__ Bp,
                                                  ushort* __restrict__ h2h) {
    int t = threadIdx.x;
    int lane = t & 63, w = t >> 6;
    int r = lane & 15, q = lane >> 4;
    int row0 = blockIdx.x * 64;
    int arow = row0 + w * 16 + r;            // rows < ROWS_PAD, buffer padded
    f32x4 acc[3] = {};
    for (int kt = 0; kt < 4; ++kt) {
        half8 a = *(const half8*)(hagh + (size_t)arow * HIDDEN + kt * 32 + q * 8);
#pragma unroll
        for (int nt = 0; nt < 3; ++nt) {
            half8 b = *(const half8*)(Bp + (((nt * 4 + kt) * 64) + lane) * 8);
            acc[nt] = __builtin_amdgcn_mfma_f32_16x16x32_f16(a, b, acc[nt], 0, 0, 0);
        }
    }
#pragma unroll
    for (int nt = 0; nt < 3; ++nt) {
        int col = nt * 16 + r;
        if (col >= N_CLASSES) continue;
#pragma unroll
        for (int reg = 0; reg < 4; ++reg) {
            int row = row0 + w * 16 + q * 4 + reg;
            if (row < N_NODES) h2h[(size_t)row * H2S + col] = f2h(acc[nt][reg]);
        }
    }
}

// ---------------- layer-2 aggregation + bias + log_softmax (2 nodes/wave, __hfma2) ----------------

__global__ __launch_bounds__(256) void agg2_lsm(
        const int* __restrict__ rowptr, const int* __restrict__ deg,
        const int* __restrict__ esrc, const float* __restrict__ dinv,
        const ushort* __restrict__ h2h, const float* __restrict__ b2,
        float* __restrict__ out) {
    int t = threadIdx.x;
    int w = t >> 6, lane = t & 63;
    int half = lane >> 5, l = lane & 31;
    int v = blockIdx.x * 8 + w * 2 + half;   // grid 6250 -> v < 50000 always
    int beg = rowptr[v], d = deg[v];
    float dv = dinv[v];
    __half2 z = __float2half2_rn(0.f);
    __half2 cA = z, cB = z;
    {   // self-loop (l<20 meaningful; l>=20 reads in-row garbage, discarded)
        uint hv = *(const uint*)(h2h + (size_t)v * H2S + (l & 31) * 2);
        cA = __hfma2(u2h2(hv), __float2half2_rn(dv * dv), cA);
    }
    int e_l = (l < d) ? esrc[beg + l] : 0;
    float w_l = (l < d) ? dinv[e_l] : 0.f;
    int dm = min(d, 32);
    int base = half * 32;
    int i = 0;
    for (; i + 4 <= dm; i += 4) {
        int s0 = __shfl(e_l, base + i + 0, 64);
        int s1 = __shfl(e_l, base + i + 1, 64);
        int s2 = __shfl(e_l, base + i + 2, 64);
        int s3 = __shfl(e_l, base + i + 3, 64);
        float g0 = __shfl(w_l, base + i + 0, 64) * dv;
        float g1 = __shfl(w_l, base + i + 1, 64) * dv;
        float g2 = __shfl(w_l, base + i + 2, 64) * dv;
        float g3 = __shfl(w_l, base + i + 3, 64) * dv;
        uint h0 = *(const uint*)(h2h + (size_t)s0 * H2S + l * 2);
        uint h1 = *(const uint*)(h2h + (size_t)s1 * H2S + l * 2);
        uint h2 = *(const uint*)(h2h + (size_t)s2 * H2S + l * 2);
        uint h3 = *(const uint*)(h2h + (size_t)s3 * H2S + l * 2);
        cA = __hfma2(u2h2(h0), __float2half2_rn(g0), cA);
        cB = __hfma2(u2h2(h1), __float2half2_rn(g1), cB);
        cA = __hfma2(u2h2(h2), __float2half2_rn(g2), cA);
        cB = __hfma2(u2h2(h3), __float2half2_rn(g3), cB);
    }
    for (; i < dm; ++i) {
        int s0 = __shfl(e_l, base + i, 64);
        float g0 = __shfl(w_l, base + i, 64) * dv;
        uint h0 = *(const uint*)(h2h + (size_t)s0 * H2S + l * 2);
        cA = __hfma2(u2h2(h0), __float2half2_rn(g0), cA);
    }
    for (i = 32; i < d; ++i) {               // rare deg>32 tail
        int s = esrc[beg + i];
        float g = dinv[s] * dv;
        uint hs = *(const uint*)(h2h + (size_t)s * H2S + l * 2);
        cA = __hfma2(u2h2(hs), __float2half2_rn(g), cA);
    }
    float2 fA = __half22float2(cA);
    float2 fB = __half22float2(cB);
    float ax = fA.x + fB.x, ay = fA.y + fB.y;
    if (l < 20) {
        float2 bb = ((const float2*)b2)[l];
        ax += bb.x; ay += bb.y;
    }
    float m = (l < 20) ? fmaxf(ax, ay) : -INFINITY;
#pragma unroll
    for (int off = 16; off; off >>= 1) m = fmaxf(m, __shfl_xor(m, off, 64));
    float e = (l < 20) ? (expf(ax - m) + expf(ay - m)) : 0.f;
#pragma unroll
    for (int off = 16; off; off >>= 1) e += __shfl_xor(e, off, 64);
    float ls = logf(e);
    if (l < 20) {
        float2 o;
        o.x = ax - m - ls;
        o.y = ay - m - ls;
        ((float2*)(out + (size_t)v * N_CLASSES))[l] = o;
    }
}

// ---------------- launch ----------------

extern "C" void kernel_launch(void* const* d_in, const int* in_sizes, int n_in,
                              void* d_out, int out_size, void* d_ws, size_t ws_size,
                              hipStream_t stream) {
    const float* x  = (const float*)d_in[0];
    const int*   ei = (const int*)d_in[1];
    const float* W1 = (const float*)d_in[2];
    const float* b1 = (const float*)d_in[3];
    const float* W2 = (const float*)d_in[4];
    const float* b2 = (const float*)d_in[5];
    const int* src = ei;
    const int* dst = ei + N_EDGES;
    float* out = (float*)d_out;

    char* ws = (char*)d_ws;
    size_t off = 0;
    auto alloc = [&](size_t bytes) {
        void* p = ws + off;
        off += (bytes + 255) & ~(size_t)255;
        return p;
    };
    int*    cursor = (int*)alloc((size_t)NBUCKET * 4);
    int*    deg    = (int*)alloc((size_t)N_NODES * 4);
    float*  dinv   = (float*)alloc((size_t)N_NODES * 4);
    int*    rowptr = (int*)alloc((size_t)N_NODES * 4);
    uint*   ebuf   = (uint*)alloc((size_t)NBUCKET * BCAP * 4);
    int*    esrc   = (int*)alloc((size_t)N_EDGES * 4);
    ushort* Bp1    = (ushort*)alloc((size_t)32768 * 2);
    ushort* Bp2    = (ushort*)alloc((size_t)6144 * 2);
    ushort* h1h    = (ushort*)alloc((size_t)ROWS_PAD * HIDDEN * 2);
    ushort* hagh   = (ushort*)alloc((size_t)ROWS_PAD * HIDDEN * 2);
    ushort* h2h    = (ushort*)alloc((size_t)ROWS_PAD * H2S * 2);

    // --- preprocessing: 3 kernels, no memset ---
    setup_k<<<25, 256, 0, stream>>>(W2, Bp2, cursor);
    partition_repack<<<256, 256, 0, stream>>>(src, dst, cursor, ebuf, W1, Bp1);
    bucket_csr<<<NBUCKET, 256, 0, stream>>>(ebuf, cursor, deg, dinv, rowptr, esrc);

    // --- model: 4 kernels ---
    gemm1_mfma<<<ROWS_PAD / 64, 256, 0, stream>>>(x, Bp1, h1h);
    agg1_g<<<N_NODES / 4, 256, 0, stream>>>(rowptr, deg, esrc, dinv, h1h, b1, hagh);
    gemm2_mfma<<<ROWS_PAD / 64, 256, 0, stream>>>(hagh, Bp2, h2h);
    agg2_lsm<<<N_NODES / 8, 256, 0, stream>>>(rowptr, deg, esrc, dinv, h2h, b2, out);
}